// Round 6
// baseline (22073.483 us; speedup 1.0000x reference)
//
#include <hip/hip_runtime.h>

#define Bsz  128
#define Tlen 96
#define Edim 512
#define Ddim 512
#define Adim 512
#define EMBd 512
#define Vdim 4096

typedef __attribute__((ext_vector_type(8))) short short8v;
typedef __attribute__((ext_vector_type(4))) float f32x4;

__device__ __forceinline__ float sigm(float x) { return 1.0f / (1.0f + expf(-x)); }
__device__ __forceinline__ unsigned short f2bf(float f) {
    unsigned int x = __float_as_uint(f);
    unsigned int r = (x + 0x7FFFu + ((x >> 16) & 1u)) >> 16;
    return (unsigned short)r;
}

// ---------------------------------------------------------------------------
// Stable descending sort by length (matches jnp.argsort(-lens), stable).
// Also zeroes the grid-barrier counter (workspace is poisoned every launch).
__global__ void k_sort(const int* __restrict__ lens, int* __restrict__ order,
                       int* __restrict__ lens_s, unsigned int* __restrict__ bar) {
    __shared__ int L[Bsz];
    int j = threadIdx.x;
    if (j == 0) bar[0] = 0u;
    L[j] = lens[j];
    __syncthreads();
    int lj = L[j];
    int rank = 0;
    for (int m = 0; m < Bsz; ++m) {
        int lm = L[m];
        if (lm > lj || (lm == lj && m < j)) rank++;
    }
    order[rank] = j;
    lens_s[rank] = lj;
}

// Gather sorted encoder rows.
__global__ void k_gather(const float* __restrict__ enc_in,
                         const int* __restrict__ order, float* __restrict__ enc_s) {
    int i = blockIdx.x;
    int src = order[i];
    for (int d = threadIdx.x; d < Edim; d += 256)
        enc_s[i * Edim + d] = enc_in[src * Edim + d];
}

// fp32 -> bf16 weight conversion (W_fc), run every call.
__global__ void k_cvtW(const float* __restrict__ W, unsigned short* __restrict__ O,
                       int n) {
    int i = blockIdx.x * 256 + threadIdx.x;
    if (i < n) O[i] = f2bf(W[i]);
}

// ---------------------------------------------------------------------------
// Tiled fp32 matmul: block computes 64x64 tile of  act[128xK] @ W[NxK]^T.
__device__ __forceinline__ void mm_tile(const float* __restrict__ act,
                                        const float* __restrict__ W,
                                        int K, int i0, float acc[4][4]) {
    __shared__ float sA[64][17];
    __shared__ float sB[64][17];
    int tid = threadIdx.x;
    int tx = tid & 15, ty = tid >> 4;
    for (int k0 = 0; k0 < K; k0 += 16) {
        {
            int idx = tid * 4;
            int row = idx >> 4;
            int kk = idx & 15;
            const float* p = act + (size_t)(i0 + row) * K + k0 + kk;
            float4 v = *reinterpret_cast<const float4*>(p);
            sA[row][kk + 0] = v.x; sA[row][kk + 1] = v.y;
            sA[row][kk + 2] = v.z; sA[row][kk + 3] = v.w;
        }
        {
            int idx = tid * 4;
            int row = idx >> 4;
            int kk = idx & 15;
            const float* p = W + (size_t)row * K + k0 + kk;
            float4 v = *reinterpret_cast<const float4*>(p);
            sB[row][kk + 0] = v.x; sB[row][kk + 1] = v.y;
            sB[row][kk + 2] = v.z; sB[row][kk + 3] = v.w;
        }
        __syncthreads();
#pragma unroll
        for (int kk = 0; kk < 16; ++kk) {
            float a[4], b[4];
#pragma unroll
            for (int r = 0; r < 4; ++r) a[r] = sA[ty * 4 + r][kk];
#pragma unroll
            for (int cidx = 0; cidx < 4; ++cidx) b[cidx] = sB[tx * 4 + cidx][kk];
#pragma unroll
            for (int r = 0; r < 4; ++r)
#pragma unroll
                for (int cidx = 0; cidx < 4; ++cidx)
                    acc[r][cidx] += a[r] * b[cidx];
        }
        __syncthreads();
    }
}

// ---------------------------------------------------------------------------
// Init: h0 | c0 | att1  =  enc_s @ [W_init_h | W_init_c | W_enc]^T + biases
__global__ __launch_bounds__(256) void k_init(
    const float* __restrict__ enc_s,
    const float* __restrict__ W_init_h, const float* __restrict__ b_init_h,
    const float* __restrict__ W_init_c, const float* __restrict__ b_init_c,
    const float* __restrict__ W_enc, const float* __restrict__ b_enc,
    float* __restrict__ h, float* __restrict__ c, float* __restrict__ att1) {
    int j0 = blockIdx.x * 64;
    int i0 = blockIdx.y * 64;
    const float* W; const float* bias; float* out; int jl;
    if (j0 < 512)       { W = W_init_h; bias = b_init_h; out = h;    jl = j0; }
    else if (j0 < 1024) { W = W_init_c; bias = b_init_c; out = c;    jl = j0 - 512; }
    else                { W = W_enc;    bias = b_enc;    out = att1; jl = j0 - 1024; }
    float acc[4][4] = {};
    mm_tile(enc_s, W + (size_t)jl * Edim, Edim, i0, acc);
    int tx = threadIdx.x & 15, ty = threadIdx.x >> 4;
#pragma unroll
    for (int r = 0; r < 4; ++r)
#pragma unroll
        for (int cc = 0; cc < 4; ++cc) {
            int i = i0 + ty * 4 + r, j = jl + tx * 4 + cc;
            out[i * 512 + j] = acc[r][cc] + bias[j];
        }
}

// ---------------------------------------------------------------------------
// Software grid barrier (device-scope). Monotonic counter, one atomic/block.
// Release fence before arrive (flush XCD L2), acquire fence after the spin
// (invalidate stale lines) -- same primitive cg::grid_group::sync uses.
#define NBLK 128
__device__ __forceinline__ void gbar(unsigned int* bar, unsigned int target) {
    __syncthreads();
    if (threadIdx.x == 0) {
        __threadfence();
        __hip_atomic_fetch_add(bar, 1u, __ATOMIC_RELEASE, __HIP_MEMORY_SCOPE_AGENT);
        while (__hip_atomic_load(bar, __ATOMIC_ACQUIRE, __HIP_MEMORY_SCOPE_AGENT)
               < target)
            __builtin_amdgcn_s_sleep(1);
        __threadfence();
    }
    __syncthreads();
}

// ---------------------------------------------------------------------------
// The whole 96-step recurrence in ONE persistent kernel. 128 blocks x 256 thr.
struct LoopArgs {
    const float* att1; const float* enc_s;
    const float* W_dec; const float* b_dec;
    const float* W_fbeta; const float* b_fbeta;
    const float* W_hh; const float* b_hh;
    const float* W_full; const float* b_full;
    const float* emb_table;
    const int* caps; const int* order; const int* lens_s;
    const float* W_ih; const float* b_ih;
    float* h; float* c; float* att2; float* gate; float* hh;
    float* x; float* gates;
    unsigned short* h_hist;
    unsigned int* bar;
};

__global__ __launch_bounds__(256) void k_loop(LoopArgs A) {
    int bid = blockIdx.x;
    int tid = threadIdx.x;
    unsigned int barno = 0;
    __shared__ float sWF[512];
    __shared__ float sA2[512];
    __shared__ float sSC[128];
    __shared__ float sRed[2];
    for (int d = tid; d < 512; d += 256) sWF[d] = A.W_full[d];
    float bfull = A.b_full[0];

    for (int t = 0; t < Tlen; ++t) {
        // ---- phase A: att2 | gate | hh  = h @ [W_dec|W_fbeta|W_hh]^T + bias
        if (bid < 96) {
            int j0 = (bid >> 1) * 64;
            int i0 = (bid & 1) * 64;
            int tx = tid & 15, ty = tid >> 4;
            if (j0 < 512) {
                float acc[4][4] = {};
                mm_tile(A.h, A.W_dec + (size_t)j0 * Ddim, Ddim, i0, acc);
#pragma unroll
                for (int r = 0; r < 4; ++r)
#pragma unroll
                    for (int cc = 0; cc < 4; ++cc) {
                        int i = i0 + ty * 4 + r, j = j0 + tx * 4 + cc;
                        A.att2[i * 512 + j] = acc[r][cc] + A.b_dec[j];
                    }
            } else if (j0 < 1024) {
                float acc[4][4] = {};
                int jl = j0 - 512;
                mm_tile(A.h, A.W_fbeta + (size_t)jl * Ddim, Ddim, i0, acc);
#pragma unroll
                for (int r = 0; r < 4; ++r)
#pragma unroll
                    for (int cc = 0; cc < 4; ++cc) {
                        int i = i0 + ty * 4 + r, j = jl + tx * 4 + cc;
                        A.gate[i * 512 + j] = sigm(acc[r][cc] + A.b_fbeta[j]);
                    }
            } else {
                float acc[4][4] = {};
                int jl = j0 - 1024;
                mm_tile(A.h, A.W_hh + (size_t)jl * Ddim, Ddim, i0, acc);
#pragma unroll
                for (int r = 0; r < 4; ++r)
#pragma unroll
                    for (int cc = 0; cc < 4; ++cc) {
                        int i = i0 + ty * 4 + r, j = jl + tx * 4 + cc;
                        A.hh[i * 2048 + j] = acc[r][cc] + A.b_hh[j];
                    }
            }
        }
        gbar(A.bar, ++barno * NBLK);

        // ---- phase B: scores -> softmax -> awe -> x = [emb, gate*awe]
        {
            int i = bid;
            for (int d = tid; d < 512; d += 256) sA2[d] = A.att2[i * 512 + d];
            __syncthreads();
            if (tid < 128) {
                int j = tid;
                const float* a1 = A.att1 + j * 512;
                float acc = 0.0f;
                for (int k = 0; k < 512; ++k) {
                    float v = a1[k] + sA2[k];
                    acc += fmaxf(v, 0.0f) * sWF[k];
                }
                float sc = acc + bfull;
                if (t >= A.lens_s[j]) sc = -1000000000.0f;
                sSC[j] = sc;
            }
            __syncthreads();
            if (tid < 64) {
                float m = fmaxf(sSC[tid], sSC[tid + 64]);
                for (int o = 32; o; o >>= 1) m = fmaxf(m, __shfl_down(m, o));
                if (tid == 0) sRed[0] = m;
            }
            __syncthreads();
            if (tid < 128) sSC[tid] = expf(sSC[tid] - sRed[0]);
            __syncthreads();
            if (tid < 64) {
                float s = sSC[tid] + sSC[tid + 64];
                for (int o = 32; o; o >>= 1) s += __shfl_down(s, o);
                if (tid == 0) sRed[1] = s;
            }
            __syncthreads();
            float inv = 1.0f / sRed[1];
            int cap = A.caps[A.order[i] * Tlen + t];
            for (int d = tid; d < 512; d += 256) {
                float acc = 0.0f;
                for (int j = 0; j < 128; ++j) acc += sSC[j] * A.enc_s[j * 512 + d];
                acc *= inv;
                A.x[i * 1024 + 512 + d] = A.gate[i * 512 + d] * acc;
                A.x[i * 1024 + d] = A.emb_table[(size_t)cap * EMBd + d];
            }
        }
        gbar(A.bar, ++barno * NBLK);

        // ---- phase C: gates = x @ W_ih^T + b_ih + hh
        if (bid < 64) {
            int j0 = (bid >> 1) * 64;
            int i0 = (bid & 1) * 64;
            float acc[4][4] = {};
            mm_tile(A.x, A.W_ih + (size_t)j0 * 1024, 1024, i0, acc);
            int tx = tid & 15, ty = tid >> 4;
#pragma unroll
            for (int r = 0; r < 4; ++r)
#pragma unroll
                for (int cc = 0; cc < 4; ++cc) {
                    int i = i0 + ty * 4 + r, j = j0 + tx * 4 + cc;
                    A.gates[i * 2048 + j] = acc[r][cc] + A.b_ih[j] + A.hh[i * 2048 + j];
                }
        }
        gbar(A.bar, ++barno * NBLK);

        // ---- phase D: LSTM update + bf16 h history
        {
            int i = bid;
            bool valid = t < A.lens_s[i];
            for (int d = tid; d < 512; d += 256) {
                int idx = i * 512 + d;
                float hv;
                if (valid) {
                    float gi = sigm(A.gates[i * 2048 + d]);
                    float gf = sigm(A.gates[i * 2048 + 512 + d]);
                    float gg = tanhf(A.gates[i * 2048 + 1024 + d]);
                    float go = sigm(A.gates[i * 2048 + 1536 + d]);
                    float cn = gf * A.c[idx] + gi * gg;
                    hv = go * tanhf(cn);
                    A.c[idx] = cn;
                    A.h[idx] = hv;
                } else {
                    hv = A.h[idx];
                }
                A.h_hist[(size_t)t * (Bsz * 512) + idx] = f2bf(hv);
            }
        }
        gbar(A.bar, ++barno * NBLK);
    }
}

// ---------------------------------------------------------------------------
// Batched preds GEMM: out[i,t,:] = h_hist[t,i,:] @ W_fc^T + b_fc (0 if invalid).
// M = Tlen*Bsz = 12288 rows (m = t*128 + i), N = 4096, K = 512. MFMA bf16.
__global__ __launch_bounds__(256) void k_preds(
    const unsigned short* __restrict__ hh16, const unsigned short* __restrict__ wfc16,
    const float* __restrict__ b_fc, const int* __restrict__ lens_s,
    float* __restrict__ out) {
    int nb = blockIdx.x;            // 0..31
    int mb = blockIdx.y;            // 0..95
    int wid = threadIdx.x >> 6;
    int lane = threadIdx.x & 63;
    int wr = wid >> 1, wc = wid & 1;
    int m_wave = mb * 128 + wr * 64;
    int n_wave = nb * 128 + wc * 64;
    int r = lane & 15, g = lane >> 4;
    f32x4 acc[4][4];
#pragma unroll
    for (int a = 0; a < 4; ++a)
#pragma unroll
        for (int b = 0; b < 4; ++b) acc[a][b] = (f32x4){0.f, 0.f, 0.f, 0.f};
    for (int kk = 0; kk < 512; kk += 32) {
        short8v av[4], bv[4];
#pragma unroll
        for (int mf = 0; mf < 4; ++mf)
            av[mf] = *reinterpret_cast<const short8v*>(
                &hh16[(size_t)(m_wave + mf * 16 + r) * 512 + kk + g * 8]);
#pragma unroll
        for (int nf = 0; nf < 4; ++nf)
            bv[nf] = *reinterpret_cast<const short8v*>(
                &wfc16[(size_t)(n_wave + nf * 16 + r) * 512 + kk + g * 8]);
#pragma unroll
        for (int mf = 0; mf < 4; ++mf)
#pragma unroll
            for (int nf = 0; nf < 4; ++nf)
                acc[mf][nf] = __builtin_amdgcn_mfma_f32_16x16x32_bf16(
                    av[mf], bv[nf], acc[mf][nf], 0, 0, 0);
    }
#pragma unroll
    for (int mf = 0; mf < 4; ++mf)
#pragma unroll
        for (int nf = 0; nf < 4; ++nf)
#pragma unroll
            for (int reg = 0; reg < 4; ++reg) {
                int m = m_wave + mf * 16 + g * 4 + reg;  // row = (lane>>4)*4+reg
                int col = n_wave + nf * 16 + r;          // col = lane&15
                int t = m >> 7, i = m & 127;
                bool valid = t < lens_s[i];
                out[((size_t)i * Tlen + t) * Vdim + col] =
                    valid ? acc[mf][nf][reg] + b_fc[col] : 0.0f;
            }
}

// ---------------------------------------------------------------------------
extern "C" void kernel_launch(void* const* d_in, const int* in_sizes, int n_in,
                              void* d_out, int out_size, void* d_ws, size_t ws_size,
                              hipStream_t stream) {
    const float* encoder_out = (const float*)d_in[0];
    const int* caps = (const int*)d_in[1];
    const int* lens = (const int*)d_in[2];
    const float* W_enc = (const float*)d_in[3];
    const float* b_enc = (const float*)d_in[4];
    const float* W_dec = (const float*)d_in[5];
    const float* b_dec = (const float*)d_in[6];
    const float* W_full = (const float*)d_in[7];
    const float* b_full = (const float*)d_in[8];
    const float* W_init_h = (const float*)d_in[9];
    const float* b_init_h = (const float*)d_in[10];
    const float* W_init_c = (const float*)d_in[11];
    const float* b_init_c = (const float*)d_in[12];
    const float* W_fbeta = (const float*)d_in[13];
    const float* b_fbeta = (const float*)d_in[14];
    const float* W_fc = (const float*)d_in[15];
    const float* b_fc = (const float*)d_in[16];
    const float* emb_table = (const float*)d_in[17];
    const float* W_ih = (const float*)d_in[18];
    const float* b_ih = (const float*)d_in[19];
    const float* W_hh = (const float*)d_in[20];
    const float* b_hh = (const float*)d_in[21];
    float* out = (float*)d_out;

    char* p = (char*)d_ws;
    auto alloc = [&](size_t bytes) {
        void* r = (void*)p;
        p += (bytes + 255) & ~(size_t)255;
        return r;
    };
    int* order = (int*)alloc(Bsz * 4);
    int* lens_s = (int*)alloc(Bsz * 4);
    unsigned int* bar = (unsigned int*)alloc(256);
    float* enc_s = (float*)alloc(Bsz * Edim * 4);
    float* att1 = (float*)alloc(Bsz * Adim * 4);
    float* h = (float*)alloc(Bsz * Ddim * 4);
    float* c = (float*)alloc(Bsz * Ddim * 4);
    float* att2 = (float*)alloc(Bsz * Adim * 4);
    float* gate = (float*)alloc(Bsz * Ddim * 4);
    float* hh = (float*)alloc(Bsz * 2048 * 4);
    float* x = (float*)alloc(Bsz * 1024 * 4);
    float* gates = (float*)alloc(Bsz * 2048 * 4);
    unsigned short* h_hist = (unsigned short*)alloc((size_t)Tlen * Bsz * 512 * 2);
    unsigned short* wfc16 = (unsigned short*)alloc((size_t)Vdim * Ddim * 2);

    k_sort<<<1, 128, 0, stream>>>(lens, order, lens_s, bar);
    k_gather<<<Bsz, 256, 0, stream>>>(encoder_out, order, enc_s);
    k_cvtW<<<(Vdim * Ddim + 255) / 256, 256, 0, stream>>>(W_fc, wfc16, Vdim * Ddim);
    k_init<<<dim3(24, 2), 256, 0, stream>>>(enc_s, W_init_h, b_init_h, W_init_c,
                                            b_init_c, W_enc, b_enc, h, c, att1);

    LoopArgs la;
    la.att1 = att1; la.enc_s = enc_s;
    la.W_dec = W_dec; la.b_dec = b_dec;
    la.W_fbeta = W_fbeta; la.b_fbeta = b_fbeta;
    la.W_hh = W_hh; la.b_hh = b_hh;
    la.W_full = W_full; la.b_full = b_full;
    la.emb_table = emb_table;
    la.caps = caps; la.order = order; la.lens_s = lens_s;
    la.W_ih = W_ih; la.b_ih = b_ih;
    la.h = h; la.c = c; la.att2 = att2; la.gate = gate; la.hh = hh;
    la.x = x; la.gates = gates;
    la.h_hist = h_hist;
    la.bar = bar;
    k_loop<<<NBLK, 256, 0, stream>>>(la);

    k_preds<<<dim3(32, 96), 256, 0, stream>>>(h_hist, wfc16, b_fc, lens_s, out);
}

// Round 7
// 11463.748 us; speedup vs baseline: 1.9255x; 1.9255x over previous
//
#include <hip/hip_runtime.h>

#define Bsz  128
#define Tlen 96
#define Edim 512
#define Ddim 512
#define Adim 512
#define EMBd 512
#define Vdim 4096
#define NBLK 192

typedef __attribute__((ext_vector_type(8))) short short8v;
typedef __attribute__((ext_vector_type(4))) float f32x4;

__device__ __forceinline__ float sigm(float x) { return 1.0f / (1.0f + expf(-x)); }
__device__ __forceinline__ unsigned short f2bf(float f) {
    unsigned int x = __float_as_uint(f);
    unsigned int r = (x + 0x7FFFu + ((x >> 16) & 1u)) >> 16;
    return (unsigned short)r;
}
__device__ __forceinline__ unsigned int pack2(float a, float b) {
    return (unsigned int)f2bf(a) | ((unsigned int)f2bf(b) << 16);
}

// ---- agent-scope (cross-XCD coherent, cache-bypassing) accessors ----------
__device__ __forceinline__ float gldf(const float* p) {
    return __hip_atomic_load(p, __ATOMIC_RELAXED, __HIP_MEMORY_SCOPE_AGENT);
}
__device__ __forceinline__ void gstf(float* p, float v) {
    __hip_atomic_store(p, v, __ATOMIC_RELAXED, __HIP_MEMORY_SCOPE_AGENT);
}
__device__ __forceinline__ unsigned long long gldq(const void* p) {
    return __hip_atomic_load((const unsigned long long*)p, __ATOMIC_RELAXED,
                             __HIP_MEMORY_SCOPE_AGENT);
}
__device__ __forceinline__ void gstu(unsigned int* p, unsigned int v) {
    __hip_atomic_store(p, v, __ATOMIC_RELAXED, __HIP_MEMORY_SCOPE_AGENT);
}
__device__ __forceinline__ unsigned int gldu(const unsigned int* p) {
    return __hip_atomic_load(p, __ATOMIC_RELAXED, __HIP_MEMORY_SCOPE_AGENT);
}
// 8 bf16 via two 8-byte agent loads (16B-aligned addresses)
__device__ __forceinline__ short8v ald8(const unsigned short* p) {
    union { unsigned long long q[2]; short8v v; } u;
    u.q[0] = gldq(p);
    u.q[1] = gldq(p + 4);
    return u.v;
}

// ---------------------------------------------------------------------------
// Stable descending sort by length (matches jnp.argsort(-lens), stable).
// Also zeroes the grid-barrier counter (workspace is poisoned every launch).
__global__ void k_sort(const int* __restrict__ lens, int* __restrict__ order,
                       int* __restrict__ lens_s, unsigned int* __restrict__ bar) {
    __shared__ int L[Bsz];
    int j = threadIdx.x;
    if (j == 0) bar[0] = 0u;
    L[j] = lens[j];
    __syncthreads();
    int lj = L[j];
    int rank = 0;
    for (int m = 0; m < Bsz; ++m) {
        int lm = L[m];
        if (lm > lj || (lm == lj && m < j)) rank++;
    }
    order[rank] = j;
    lens_s[rank] = lj;
}

// Gather sorted encoder rows.
__global__ void k_gather(const float* __restrict__ enc_in,
                         const int* __restrict__ order, float* __restrict__ enc_s) {
    int i = blockIdx.x;
    int src = order[i];
    for (int d = threadIdx.x; d < Edim; d += 256)
        enc_s[i * Edim + d] = enc_in[src * Edim + d];
}

// fp32 -> bf16 weight conversion, run every call.
__global__ void k_cvtW(const float* __restrict__ W, unsigned short* __restrict__ O,
                       int n) {
    int i = blockIdx.x * 256 + threadIdx.x;
    if (i < n) O[i] = f2bf(W[i]);
}

// ---------------------------------------------------------------------------
// Tiled fp32 matmul for k_init only (runs once; accuracy of h0/c0/att1 kept fp32).
__device__ __forceinline__ void mm_tile(const float* __restrict__ act,
                                        const float* __restrict__ W,
                                        int K, int i0, float acc[4][4]) {
    __shared__ float sA[64][17];
    __shared__ float sB[64][17];
    int tid = threadIdx.x;
    int tx = tid & 15, ty = tid >> 4;
    for (int k0 = 0; k0 < K; k0 += 16) {
        {
            int idx = tid * 4;
            int row = idx >> 4;
            int kk = idx & 15;
            const float* p = act + (size_t)(i0 + row) * K + k0 + kk;
            float4 v = *reinterpret_cast<const float4*>(p);
            sA[row][kk + 0] = v.x; sA[row][kk + 1] = v.y;
            sA[row][kk + 2] = v.z; sA[row][kk + 3] = v.w;
        }
        {
            int idx = tid * 4;
            int row = idx >> 4;
            int kk = idx & 15;
            const float* p = W + (size_t)row * K + k0 + kk;
            float4 v = *reinterpret_cast<const float4*>(p);
            sB[row][kk + 0] = v.x; sB[row][kk + 1] = v.y;
            sB[row][kk + 2] = v.z; sB[row][kk + 3] = v.w;
        }
        __syncthreads();
#pragma unroll
        for (int kk = 0; kk < 16; ++kk) {
            float a[4], b[4];
#pragma unroll
            for (int r = 0; r < 4; ++r) a[r] = sA[ty * 4 + r][kk];
#pragma unroll
            for (int c = 0; c < 4; ++c) b[c] = sB[tx * 4 + c][kk];
#pragma unroll
            for (int r = 0; r < 4; ++r)
#pragma unroll
                for (int c = 0; c < 4; ++c)
                    acc[r][c] += a[r] * b[c];
        }
        __syncthreads();
    }
}

// Init: h0(->bf16) | c0 | att1  =  enc_s @ [W_init_h | W_init_c | W_enc]^T + b
__global__ __launch_bounds__(256) void k_init(
    const float* __restrict__ enc_s,
    const float* __restrict__ W_init_h, const float* __restrict__ b_init_h,
    const float* __restrict__ W_init_c, const float* __restrict__ b_init_c,
    const float* __restrict__ W_enc, const float* __restrict__ b_enc,
    unsigned short* __restrict__ h_bf, float* __restrict__ c,
    float* __restrict__ att1) {
    int j0 = blockIdx.x * 64;
    int i0 = blockIdx.y * 64;
    const float* W; const float* bias; float* out; int jl; int mode;
    if (j0 < 512)       { W = W_init_h; bias = b_init_h; out = nullptr; jl = j0; mode = 0; }
    else if (j0 < 1024) { W = W_init_c; bias = b_init_c; out = c;    jl = j0 - 512; mode = 1; }
    else                { W = W_enc;    bias = b_enc;    out = att1; jl = j0 - 1024; mode = 1; }
    float acc[4][4] = {};
    mm_tile(enc_s, W + (size_t)jl * Edim, Edim, i0, acc);
    int tx = threadIdx.x & 15, ty = threadIdx.x >> 4;
#pragma unroll
    for (int r = 0; r < 4; ++r)
#pragma unroll
        for (int cc = 0; cc < 4; ++cc) {
            int i = i0 + ty * 4 + r, j = jl + tx * 4 + cc;
            float v = acc[r][cc] + bias[j];
            if (mode == 0) h_bf[i * 512 + j] = f2bf(v);
            else out[i * 512 + j] = v;
        }
}

// ---------------------------------------------------------------------------
// Grid barrier WITHOUT cache-invalidating fences. Producer ordering via the
// RELEASE fetch_add (drains vmcnt; writes back only dirty lines, no inv).
// Consumers re-read via agent-scope loads which bypass stale L1/L2.
__device__ __forceinline__ void gbar(unsigned int* bar, unsigned int target) {
    __syncthreads();
    if (threadIdx.x == 0) {
        asm volatile("" ::: "memory");
        __hip_atomic_fetch_add(bar, 1u, __ATOMIC_RELEASE, __HIP_MEMORY_SCOPE_AGENT);
        while (__hip_atomic_load(bar, __ATOMIC_RELAXED, __HIP_MEMORY_SCOPE_AGENT)
               < target)
            __builtin_amdgcn_s_sleep(2);
        asm volatile("" ::: "memory");
    }
    __syncthreads();
}

// ---------------------------------------------------------------------------
// The whole 96-step recurrence in ONE persistent kernel. 192 blocks x 256 thr.
// Weights cached (bf16, L2-resident); activations via agent-scope atomics.
struct LoopArgs {
    const float* att1; const float* enc_s;
    const unsigned short* Wcat;               // [3072][512] = dec|fbeta|hh
    const unsigned short* Wih;                // [2048][1024]
    const float* b_dec; const float* b_fbeta; const float* b_hh; const float* b_ih;
    const float* W_full; const float* b_full;
    const float* emb_table;
    const int* caps; const int* order; const int* lens_s;
    unsigned short* h_bf;                     // [128][512]
    float* c;
    float* att2; float* gate; float* hh; float* gates;
    unsigned short* x_bf;                     // [128][1024]
    unsigned short* h_hist;                   // [96][128][512]
    unsigned int* bar;
};

__global__ __launch_bounds__(256) void k_loop(LoopArgs A) {
    int bid = blockIdx.x;
    int tid = threadIdx.x;
    int lane = tid & 63, w = tid >> 6;
    int r = lane & 15, g = lane >> 4;
    unsigned int barno = 0;
    __shared__ float sWF[512];
    __shared__ float sA2[512];
    __shared__ float sSC[128];
    __shared__ float sRed[2];
    for (int d = tid; d < 512; d += 256) sWF[d] = A.W_full[d];
    float bfull = A.b_full[0];

    for (int t = 0; t < Tlen; ++t) {
        // ---- phase A: [att2|gate|hh] = h_bf @ Wcat^T + bias  (MFMA bf16)
        if (bid < 192) {
            int j0 = bid * 16;
            int row0 = w * 32;
            const unsigned short* ar0 = A.h_bf + (size_t)(row0 + r) * 512 + g * 8;
            const unsigned short* ar1 = ar0 + 16 * 512;
            const unsigned short* br  = A.Wcat + (size_t)(j0 + r) * 512 + g * 8;
            f32x4 acc0 = {0.f, 0.f, 0.f, 0.f}, acc1 = {0.f, 0.f, 0.f, 0.f};
#pragma unroll 4
            for (int kc = 0; kc < 16; ++kc) {
                short8v a0 = ald8(ar0 + kc * 32);
                short8v a1 = ald8(ar1 + kc * 32);
                short8v b = *reinterpret_cast<const short8v*>(br + kc * 32);
                acc0 = __builtin_amdgcn_mfma_f32_16x16x32_bf16(a0, b, acc0, 0, 0, 0);
                acc1 = __builtin_amdgcn_mfma_f32_16x16x32_bf16(a1, b, acc1, 0, 0, 0);
            }
            int n = j0 + r;
            int seg; float bias;
            if (n < 512)       { seg = 0; bias = A.b_dec[n]; }
            else if (n < 1024) { seg = 1; bias = A.b_fbeta[n - 512]; }
            else               { seg = 2; bias = A.b_hh[n - 1024]; }
#pragma unroll
            for (int reg = 0; reg < 4; ++reg) {
                int m = row0 + g * 4 + reg;
                float v = acc0[reg] + bias;
                if (seg == 0)      gstf(&A.att2[m * 512 + n], v);
                else if (seg == 1) gstf(&A.gate[m * 512 + (n - 512)], sigm(v));
                else               gstf(&A.hh[m * 2048 + (n - 1024)], v);
            }
#pragma unroll
            for (int reg = 0; reg < 4; ++reg) {
                int m = row0 + 16 + g * 4 + reg;
                float v = acc1[reg] + bias;
                if (seg == 0)      gstf(&A.att2[m * 512 + n], v);
                else if (seg == 1) gstf(&A.gate[m * 512 + (n - 512)], sigm(v));
                else               gstf(&A.hh[m * 2048 + (n - 1024)], v);
            }
        }
        gbar(A.bar, ++barno * NBLK);

        // ---- phase B: scores -> softmax(keys) -> awe -> x_bf = [emb, gate*awe]
        if (bid < 128) {
            int i = bid;
            {
                int d0 = tid * 2;
                unsigned long long q = gldq(&A.att2[i * 512 + d0]);
                sA2[d0] = __uint_as_float((unsigned int)q);
                sA2[d0 + 1] = __uint_as_float((unsigned int)(q >> 32));
            }
            __syncthreads();
            if (tid < 128) {
                const float* a1 = A.att1 + tid * 512;
                float acc = 0.0f;
#pragma unroll 4
                for (int k = 0; k < 512; ++k)
                    acc += fmaxf(a1[k] + sA2[k], 0.0f) * sWF[k];
                float sc = acc + bfull;
                if (t >= A.lens_s[tid]) sc = -1000000000.0f;
                sSC[tid] = sc;
            }
            __syncthreads();
            if (tid < 64) {
                float m = fmaxf(sSC[tid], sSC[tid + 64]);
                for (int o = 32; o; o >>= 1) m = fmaxf(m, __shfl_down(m, o));
                if (tid == 0) sRed[0] = m;
            }
            __syncthreads();
            if (tid < 128) sSC[tid] = expf(sSC[tid] - sRed[0]);
            __syncthreads();
            if (tid < 64) {
                float s = sSC[tid] + sSC[tid + 64];
                for (int o = 32; o; o >>= 1) s += __shfl_down(s, o);
                if (tid == 0) sRed[1] = s;
            }
            __syncthreads();
            float inv = 1.0f / sRed[1];
            int cap = A.caps[A.order[i] * Tlen + t];
            int d0 = tid * 2;
            float aw0 = 0.f, aw1 = 0.f;
#pragma unroll 4
            for (int j = 0; j < 128; ++j) {
                float al = sSC[j];
                aw0 += al * A.enc_s[j * 512 + d0];
                aw1 += al * A.enc_s[j * 512 + d0 + 1];
            }
            unsigned long long gq = gldq(&A.gate[i * 512 + d0]);
            float g0 = __uint_as_float((unsigned int)gq);
            float g1 = __uint_as_float((unsigned int)(gq >> 32));
            gstu((unsigned int*)A.x_bf + ((i * 1024 + 512 + d0) >> 1),
                 pack2(g0 * aw0 * inv, g1 * aw1 * inv));
            float e0 = A.emb_table[(size_t)cap * EMBd + d0];
            float e1 = A.emb_table[(size_t)cap * EMBd + d0 + 1];
            gstu((unsigned int*)A.x_bf + ((i * 1024 + d0) >> 1), pack2(e0, e1));
        }
        gbar(A.bar, ++barno * NBLK);

        // ---- phase C: gates = x_bf @ Wih^T + b_ih + hh  (MFMA bf16)
        if (bid < 128) {
            int j0 = bid * 16;
            int row0 = w * 32;
            const unsigned short* ar0 = A.x_bf + (size_t)(row0 + r) * 1024 + g * 8;
            const unsigned short* ar1 = ar0 + 16 * 1024;
            const unsigned short* br  = A.Wih + (size_t)(j0 + r) * 1024 + g * 8;
            f32x4 acc0 = {0.f, 0.f, 0.f, 0.f}, acc1 = {0.f, 0.f, 0.f, 0.f};
#pragma unroll 4
            for (int kc = 0; kc < 32; ++kc) {
                short8v a0 = ald8(ar0 + kc * 32);
                short8v a1 = ald8(ar1 + kc * 32);
                short8v b = *reinterpret_cast<const short8v*>(br + kc * 32);
                acc0 = __builtin_amdgcn_mfma_f32_16x16x32_bf16(a0, b, acc0, 0, 0, 0);
                acc1 = __builtin_amdgcn_mfma_f32_16x16x32_bf16(a1, b, acc1, 0, 0, 0);
            }
            int n = j0 + r;
            float bi = A.b_ih[n];
#pragma unroll
            for (int reg = 0; reg < 4; ++reg) {
                int m = row0 + g * 4 + reg;
                float v = acc0[reg] + bi + gldf(&A.hh[m * 2048 + n]);
                gstf(&A.gates[m * 2048 + n], v);
            }
#pragma unroll
            for (int reg = 0; reg < 4; ++reg) {
                int m = row0 + 16 + g * 4 + reg;
                float v = acc1[reg] + bi + gldf(&A.hh[m * 2048 + n]);
                gstf(&A.gates[m * 2048 + n], v);
            }
        }
        gbar(A.bar, ++barno * NBLK);

        // ---- phase D: LSTM update (fp32 state) + bf16 h + history
        if (bid < 128) {
            int i = bid;
            int d0 = tid * 2;
            bool valid = t < A.lens_s[i];
            unsigned int hbits;
            if (valid) {
                int base = i * 2048;
                float gi0 = sigm(gldf(&A.gates[base + d0]));
                float gi1 = sigm(gldf(&A.gates[base + d0 + 1]));
                float gf0 = sigm(gldf(&A.gates[base + 512 + d0]));
                float gf1 = sigm(gldf(&A.gates[base + 512 + d0 + 1]));
                float gg0 = tanhf(gldf(&A.gates[base + 1024 + d0]));
                float gg1 = tanhf(gldf(&A.gates[base + 1024 + d0 + 1]));
                float go0 = sigm(gldf(&A.gates[base + 1536 + d0]));
                float go1 = sigm(gldf(&A.gates[base + 1536 + d0 + 1]));
                float c0 = gf0 * A.c[i * 512 + d0] + gi0 * gg0;
                float c1 = gf1 * A.c[i * 512 + d0 + 1] + gi1 * gg1;
                A.c[i * 512 + d0] = c0;
                A.c[i * 512 + d0 + 1] = c1;
                hbits = pack2(go0 * tanhf(c0), go1 * tanhf(c1));
                gstu((unsigned int*)A.h_bf + ((i * 512 + d0) >> 1), hbits);
            } else {
                hbits = gldu((const unsigned int*)A.h_bf + ((i * 512 + d0) >> 1));
            }
            ((unsigned int*)A.h_hist)[((size_t)t * Bsz * 512 + i * 512 + d0) >> 1] =
                hbits;  // normal store; read only by k_preds after kernel end
        }
        gbar(A.bar, ++barno * NBLK);
    }
}

// ---------------------------------------------------------------------------
// Batched preds GEMM: out[i,t,:] = h_hist[t,i,:] @ W_fc^T + b_fc (0 if invalid).
__global__ __launch_bounds__(256) void k_preds(
    const unsigned short* __restrict__ hh16, const unsigned short* __restrict__ wfc16,
    const float* __restrict__ b_fc, const int* __restrict__ lens_s,
    float* __restrict__ out) {
    int nb = blockIdx.x;            // 0..31
    int mb = blockIdx.y;            // 0..95
    int wid = threadIdx.x >> 6;
    int lane = threadIdx.x & 63;
    int wr = wid >> 1, wc = wid & 1;
    int m_wave = mb * 128 + wr * 64;
    int n_wave = nb * 128 + wc * 64;
    int r = lane & 15, g = lane >> 4;
    f32x4 acc[4][4];
#pragma unroll
    for (int a = 0; a < 4; ++a)
#pragma unroll
        for (int b = 0; b < 4; ++b) acc[a][b] = (f32x4){0.f, 0.f, 0.f, 0.f};
    for (int kk = 0; kk < 512; kk += 32) {
        short8v av[4], bv[4];
#pragma unroll
        for (int mf = 0; mf < 4; ++mf)
            av[mf] = *reinterpret_cast<const short8v*>(
                &hh16[(size_t)(m_wave + mf * 16 + r) * 512 + kk + g * 8]);
#pragma unroll
        for (int nf = 0; nf < 4; ++nf)
            bv[nf] = *reinterpret_cast<const short8v*>(
                &wfc16[(size_t)(n_wave + nf * 16 + r) * 512 + kk + g * 8]);
#pragma unroll
        for (int mf = 0; mf < 4; ++mf)
#pragma unroll
            for (int nf = 0; nf < 4; ++nf)
                acc[mf][nf] = __builtin_amdgcn_mfma_f32_16x16x32_bf16(
                    av[mf], bv[nf], acc[mf][nf], 0, 0, 0);
    }
#pragma unroll
    for (int mf = 0; mf < 4; ++mf)
#pragma unroll
        for (int nf = 0; nf < 4; ++nf)
#pragma unroll
            for (int reg = 0; reg < 4; ++reg) {
                int m = m_wave + mf * 16 + g * 4 + reg;
                int col = n_wave + nf * 16 + r;
                int t = m >> 7, i = m & 127;
                bool valid = t < lens_s[i];
                out[((size_t)i * Tlen + t) * Vdim + col] =
                    valid ? acc[mf][nf][reg] + b_fc[col] : 0.0f;
            }
}

// ---------------------------------------------------------------------------
extern "C" void kernel_launch(void* const* d_in, const int* in_sizes, int n_in,
                              void* d_out, int out_size, void* d_ws, size_t ws_size,
                              hipStream_t stream) {
    const float* encoder_out = (const float*)d_in[0];
    const int* caps = (const int*)d_in[1];
    const int* lens = (const int*)d_in[2];
    const float* W_enc = (const float*)d_in[3];
    const float* b_enc = (const float*)d_in[4];
    const float* W_dec = (const float*)d_in[5];
    const float* b_dec = (const float*)d_in[6];
    const float* W_full = (const float*)d_in[7];
    const float* b_full = (const float*)d_in[8];
    const float* W_init_h = (const float*)d_in[9];
    const float* b_init_h = (const float*)d_in[10];
    const float* W_init_c = (const float*)d_in[11];
    const float* b_init_c = (const float*)d_in[12];
    const float* W_fbeta = (const float*)d_in[13];
    const float* b_fbeta = (const float*)d_in[14];
    const float* W_fc = (const float*)d_in[15];
    const float* b_fc = (const float*)d_in[16];
    const float* emb_table = (const float*)d_in[17];
    const float* W_ih = (const float*)d_in[18];
    const float* b_ih = (const float*)d_in[19];
    const float* W_hh = (const float*)d_in[20];
    const float* b_hh = (const float*)d_in[21];
    float* out = (float*)d_out;

    char* p = (char*)d_ws;
    auto alloc = [&](size_t bytes) {
        void* r = (void*)p;
        p += (bytes + 255) & ~(size_t)255;
        return r;
    };
    int* order = (int*)alloc(Bsz * 4);
    int* lens_s = (int*)alloc(Bsz * 4);
    unsigned int* bar = (unsigned int*)alloc(256);
    float* enc_s = (float*)alloc(Bsz * Edim * 4);
    float* att1 = (float*)alloc(Bsz * Adim * 4);
    float* c = (float*)alloc(Bsz * Ddim * 4);
    float* att2 = (float*)alloc(Bsz * Adim * 4);
    float* gate = (float*)alloc(Bsz * Ddim * 4);
    float* hh = (float*)alloc(Bsz * 2048 * 4);
    float* gates = (float*)alloc(Bsz * 2048 * 4);
    unsigned short* h_bf = (unsigned short*)alloc(Bsz * 512 * 2);
    unsigned short* x_bf = (unsigned short*)alloc(Bsz * 1024 * 2);
    unsigned short* h_hist = (unsigned short*)alloc((size_t)Tlen * Bsz * 512 * 2);
    unsigned short* Wcat = (unsigned short*)alloc((size_t)3072 * 512 * 2);
    unsigned short* Wih16 = (unsigned short*)alloc((size_t)2048 * 1024 * 2);
    unsigned short* wfc16 = (unsigned short*)alloc((size_t)Vdim * Ddim * 2);

    k_sort<<<1, 128, 0, stream>>>(lens, order, lens_s, bar);
    k_gather<<<Bsz, 256, 0, stream>>>(encoder_out, order, enc_s);
    // bf16 weight packs: Wcat = [W_dec | W_fbeta | W_hh] rows, K=512
    k_cvtW<<<(512 * 512 + 255) / 256, 256, 0, stream>>>(W_dec, Wcat, 512 * 512);
    k_cvtW<<<(512 * 512 + 255) / 256, 256, 0, stream>>>(W_fbeta, Wcat + 512 * 512,
                                                        512 * 512);
    k_cvtW<<<(2048 * 512 + 255) / 256, 256, 0, stream>>>(W_hh, Wcat + 1024 * 512,
                                                         2048 * 512);
    k_cvtW<<<(2048 * 1024 + 255) / 256, 256, 0, stream>>>(W_ih, Wih16, 2048 * 1024);
    k_cvtW<<<(Vdim * Ddim + 255) / 256, 256, 0, stream>>>(W_fc, wfc16, Vdim * Ddim);
    k_init<<<dim3(24, 2), 256, 0, stream>>>(enc_s, W_init_h, b_init_h, W_init_c,
                                            b_init_c, W_enc, b_enc, h_bf, c, att1);

    LoopArgs la;
    la.att1 = att1; la.enc_s = enc_s;
    la.Wcat = Wcat; la.Wih = Wih16;
    la.b_dec = b_dec; la.b_fbeta = b_fbeta; la.b_hh = b_hh; la.b_ih = b_ih;
    la.W_full = W_full; la.b_full = b_full;
    la.emb_table = emb_table;
    la.caps = caps; la.order = order; la.lens_s = lens_s;
    la.h_bf = h_bf; la.c = c;
    la.att2 = att2; la.gate = gate; la.hh = hh; la.gates = gates;
    la.x_bf = x_bf; la.h_hist = h_hist;
    la.bar = bar;
    k_loop<<<NBLK, 256, 0, stream>>>(la);

    k_preds<<<dim3(32, 96), 256, 0, stream>>>(h_hist, wfc16, b_fc, lens_s, out);
}